// Round 1
// baseline (1476.592 us; speedup 1.0000x reference)
//
#include <hip/hip_runtime.h>
#include <math.h>

#define Bsz 2
#define Ssz 2048
#define HIDs 3072
#define NHs 16
#define NKVs 8
#define HDs 256

typedef _Float16 f16;
typedef _Float16 f16x8 __attribute__((ext_vector_type(8)));
typedef _Float16 f16x4 __attribute__((ext_vector_type(4)));
typedef float f32x4 __attribute__((ext_vector_type(4)));

// ---------------- cast fp32 -> fp16 (vectorized x4) ----------------
__global__ void cast_f32_f16_v4(const float4* __restrict__ in, f16x4* __restrict__ out, int n4) {
    int i = blockIdx.x * blockDim.x + threadIdx.x;
    if (i < n4) {
        float4 v = in[i];
        f16x4 r;
        r[0] = (f16)v.x; r[1] = (f16)v.y; r[2] = (f16)v.z; r[3] = (f16)v.w;
        out[i] = r;
    }
}

// ---------------- NT GEMM: C[M,N] = A[M,K] * B[N,K]^T, fp16 in, fp32 out ----
#define GBM 128
#define GBN 128
#define GBK 32
#define GLDA 40  // padded LDS stride (bf16/f16 elems): breaks 8-way bank conflict

__global__ __launch_bounds__(256) void gemm_nt_f16(
    const f16* __restrict__ A, const f16* __restrict__ Bm, float* __restrict__ C,
    int M, int N, int K)
{
    __shared__ __align__(16) f16 As[GBM * GLDA];
    __shared__ __align__(16) f16 Bs[GBN * GLDA];
    const int tid  = threadIdx.x;
    const int wave = tid >> 6, lane = tid & 63;
    const int l15  = lane & 15, quad = lane >> 4;
    const int m0 = blockIdx.y * GBM, n0 = blockIdx.x * GBN;
    const int wm = (wave >> 1) * 64, wn = (wave & 1) * 64;
    const int row0 = tid >> 2, cc = (tid & 3) * 8;

    f32x4 acc[4][4];
    const f32x4 fz = {0.f, 0.f, 0.f, 0.f};
#pragma unroll
    for (int i = 0; i < 4; i++)
#pragma unroll
        for (int j = 0; j < 4; j++) acc[i][j] = fz;

    const f16* Ap0 = A  + (size_t)(m0 + row0) * K + cc;
    const f16* Ap1 = Ap0 + (size_t)64 * K;
    const f16* Bp0 = Bm + (size_t)(n0 + row0) * K + cc;
    const f16* Bp1 = Bp0 + (size_t)64 * K;

    for (int k0 = 0; k0 < K; k0 += GBK) {
        float4 a0 = *(const float4*)(Ap0 + k0);
        float4 a1 = *(const float4*)(Ap1 + k0);
        float4 b0 = *(const float4*)(Bp0 + k0);
        float4 b1 = *(const float4*)(Bp1 + k0);
        __syncthreads();
        *(float4*)(As + row0 * GLDA + cc)        = a0;
        *(float4*)(As + (row0 + 64) * GLDA + cc) = a1;
        *(float4*)(Bs + row0 * GLDA + cc)        = b0;
        *(float4*)(Bs + (row0 + 64) * GLDA + cc) = b1;
        __syncthreads();
        f16x8 af[4], bfr[4];
#pragma unroll
        for (int i = 0; i < 4; i++)
            af[i] = *(const f16x8*)(As + (wm + i * 16 + l15) * GLDA + quad * 8);
#pragma unroll
        for (int j = 0; j < 4; j++)
            bfr[j] = *(const f16x8*)(Bs + (wn + j * 16 + l15) * GLDA + quad * 8);
#pragma unroll
        for (int i = 0; i < 4; i++)
#pragma unroll
            for (int j = 0; j < 4; j++)
                acc[i][j] = __builtin_amdgcn_mfma_f32_16x16x32_f16(af[i], bfr[j], acc[i][j], 0, 0, 0);
    }
#pragma unroll
    for (int i = 0; i < 4; i++) {
        const int r = m0 + wm + i * 16 + quad * 4;
#pragma unroll
        for (int j = 0; j < 4; j++) {
            const int c = n0 + wn + j * 16 + l15;
#pragma unroll
            for (int rr = 0; rr < 4; rr++)
                C[(size_t)(r + rr) * N + c] = acc[i][j][rr];
        }
    }
}

// ---------------- RoPE for Q (scale 1/sqrt(HD) folded in) ----------------
__global__ void rope_q_kernel(const float* __restrict__ qp, const float* __restrict__ cosb,
                              const float* __restrict__ sinb, f16* __restrict__ qo) {
    const int s = blockIdx.x, h = blockIdx.y, b = blockIdx.z;
    const int d = threadIdx.x;
    const float* row = qp + (size_t)(b * Ssz + s) * (NHs * HDs) + h * HDs;
    float x = row[d];
    float other = (d < 128) ? -row[d + 128] : row[d - 128];
    float val = (x * cosb[s * HDs + d] + other * sinb[s * HDs + d]) * 0.0625f;
    qo[((size_t)(b * NHs + h) * Ssz + s) * HDs + d] = (f16)val;
}

// ---------------- RoPE + BFP4 quantize for K ----------------
__global__ void rope_quant_k_kernel(const float* __restrict__ kp, const float* __restrict__ cosb,
                                    const float* __restrict__ sinb, f16* __restrict__ ko) {
    const int s = blockIdx.x, h = blockIdx.y, b = blockIdx.z;
    const int d = threadIdx.x;
    const float* row = kp + (size_t)(b * Ssz + s) * (NKVs * HDs) + h * HDs;
    float x = row[d];
    float other = (d < 128) ? -row[d + 128] : row[d - 128];
    float val = x * cosb[s * HDs + d] + other * sinb[s * HDs + d];
    __shared__ float red[256];
    red[d] = fabsf(val);
    __syncthreads();
    for (int off = 64; off >= 1; off >>= 1) {
        if ((d & 127) < off) red[d] = fmaxf(red[d], red[d + off]);
        __syncthreads();
    }
    float maxabs = red[d & 128];
    float out;
    if (maxabs > 0.f) {
        int ex;
        frexpf(maxabs, &ex);             // maxabs = m*2^ex, m in [0.5,1) -> floor(log2)=ex-1 exactly
        float scale = ldexpf(1.0f, ex - 3);  // 2^(e - (bits-2)), bits=4
        float q = rintf(val / scale);        // round half-to-even, matches np.round
        q = fminf(7.f, fmaxf(-7.f, q));
        out = q * scale;                     // exactly representable in f16
    } else out = 0.f;
    ko[((size_t)(b * NKVs + h) * Ssz + s) * HDs + d] = (f16)out;
}

// ---------------- V: fp32 (b,s,kh,d) -> fp16 (b,kh,s,d) ----------------
__global__ void permute_v_kernel(const float4* __restrict__ vp, f16x4* __restrict__ vo, int n4) {
    int i = blockIdx.x * blockDim.x + threadIdx.x;
    if (i >= n4) return;
    int d4 = i & 63;
    int s  = (i >> 6) & 2047;
    int kh = (i >> 17) & 7;
    int b  = i >> 20;
    float4 v = vp[(size_t)(b * Ssz + s) * (NKVs * HDs / 4) + kh * (HDs / 4) + d4];
    f16x4 r;
    r[0] = (f16)v.x; r[1] = (f16)v.y; r[2] = (f16)v.z; r[3] = (f16)v.w;
    vo[i] = r;
}

// ---------------- flash attention: 1 wave per 32 Q rows ----------------
__global__ __launch_bounds__(64) void attn_kernel(
    const f16* __restrict__ Q,   // [B][NH][S][HD], pre-scaled by 1/16
    const f16* __restrict__ Kq,  // [B][NKV][S][HD] quantized
    const f16* __restrict__ V,   // [B][NKV][S][HD]
    f16* __restrict__ O)         // [B][S][NH*HD]
{
    const int qt = blockIdx.x, h = blockIdx.y, b = blockIdx.z;
    const int kh = h >> 1;                 // jnp.repeat: q-head h uses kv-head h/2
    const int lane = threadIdx.x;
    const int l15 = lane & 15, quad = lane >> 4;
    const int r0 = qt * 32;

    const f16* Qb = Q  + ((size_t)(b * NHs  + h)  * Ssz) * HDs;
    const f16* Kb = Kq + ((size_t)(b * NKVs + kh) * Ssz) * HDs;
    const f16* Vb = V  + ((size_t)(b * NKVs + kh) * Ssz) * HDs;

    f16x8 qf[2][8];
#pragma unroll
    for (int i = 0; i < 2; i++) {
        const f16* qrow = Qb + (size_t)(r0 + i * 16 + l15) * HDs + quad * 8;
#pragma unroll
        for (int ks = 0; ks < 8; ks++)
            qf[i][ks] = *(const f16x8*)(qrow + ks * 32);
    }

    const f32x4 fz = {0.f, 0.f, 0.f, 0.f};
    f32x4 accO[2][16];
#pragma unroll
    for (int i = 0; i < 2; i++)
#pragma unroll
        for (int jn = 0; jn < 16; jn++) accO[i][jn] = fz;
    float mrow[2][4], lrow[2][4];
#pragma unroll
    for (int i = 0; i < 2; i++)
#pragma unroll
        for (int r = 0; r < 4; r++) { mrow[i][r] = -1e30f; lrow[i][r] = 0.f; }

    __shared__ __align__(16) f16 Pl[32 * 40];   // P tile, padded stride

    for (int kt = 0; kt <= qt; kt++) {
        const int kvb = kt * 32;
        f32x4 sv[2][2];
#pragma unroll
        for (int i = 0; i < 2; i++) { sv[i][0] = fz; sv[i][1] = fz; }
        const f16* krow0 = Kb + (size_t)(kvb + l15) * HDs + quad * 8;
        const f16* krow1 = krow0 + (size_t)16 * HDs;
#pragma unroll
        for (int ks = 0; ks < 8; ks++) {
            f16x8 kf0 = *(const f16x8*)(krow0 + ks * 32);
            f16x8 kf1 = *(const f16x8*)(krow1 + ks * 32);
#pragma unroll
            for (int i = 0; i < 2; i++) {
                sv[i][0] = __builtin_amdgcn_mfma_f32_16x16x32_f16(qf[i][ks], kf0, sv[i][0], 0, 0, 0);
                sv[i][1] = __builtin_amdgcn_mfma_f32_16x16x32_f16(qf[i][ks], kf1, sv[i][1], 0, 0, 0);
            }
        }
        const bool diag = (kt == qt);
        float alpha[2][4];
#pragma unroll
        for (int i = 0; i < 2; i++) {
#pragma unroll
            for (int r = 0; r < 4; r++) {
                float s0 = sv[i][0][r], s1 = sv[i][1][r];
                if (diag) {
                    int row = r0 + i * 16 + quad * 4 + r;
                    if (kvb + l15 > row)      s0 = -1e30f;
                    if (kvb + 16 + l15 > row) s1 = -1e30f;
                }
                float rmax = fmaxf(s0, s1);
                rmax = fmaxf(rmax, __shfl_xor(rmax, 8));
                rmax = fmaxf(rmax, __shfl_xor(rmax, 4));
                rmax = fmaxf(rmax, __shfl_xor(rmax, 2));
                rmax = fmaxf(rmax, __shfl_xor(rmax, 1));
                float mold = mrow[i][r];
                float mnew = fmaxf(mold, rmax);
                float a  = __expf(mold - mnew);
                float p0 = __expf(s0 - mnew);
                float p1 = __expf(s1 - mnew);
                float rs = p0 + p1;
                rs += __shfl_xor(rs, 8);
                rs += __shfl_xor(rs, 4);
                rs += __shfl_xor(rs, 2);
                rs += __shfl_xor(rs, 1);
                lrow[i][r] = lrow[i][r] * a + rs;
                mrow[i][r] = mnew;
                alpha[i][r] = a;
                Pl[(i * 16 + quad * 4 + r) * 40 + l15]      = (f16)p0;
                Pl[(i * 16 + quad * 4 + r) * 40 + 16 + l15] = (f16)p1;
            }
        }
#pragma unroll
        for (int i = 0; i < 2; i++)
#pragma unroll
            for (int jn = 0; jn < 16; jn++) {
                f32x4 t = accO[i][jn];
                t[0] *= alpha[i][0]; t[1] *= alpha[i][1];
                t[2] *= alpha[i][2]; t[3] *= alpha[i][3];
                accO[i][jn] = t;
            }
        __syncthreads();
        // P (C-layout) -> A-layout via LDS round trip
        f16x8 pf0 = *(const f16x8*)(Pl + l15 * 40 + quad * 8);
        f16x8 pf1 = *(const f16x8*)(Pl + (16 + l15) * 40 + quad * 8);
        const f16* vbase = Vb + (size_t)(kvb + quad * 8) * HDs + l15;
#pragma unroll
        for (int jn = 0; jn < 16; jn++) {
            f16x8 vf;
#pragma unroll
            for (int j = 0; j < 8; j++) vf[j] = vbase[(size_t)j * HDs + jn * 16];
            accO[0][jn] = __builtin_amdgcn_mfma_f32_16x16x32_f16(pf0, vf, accO[0][jn], 0, 0, 0);
            accO[1][jn] = __builtin_amdgcn_mfma_f32_16x16x32_f16(pf1, vf, accO[1][jn], 0, 0, 0);
        }
        __syncthreads();
    }
#pragma unroll
    for (int i = 0; i < 2; i++) {
#pragma unroll
        for (int r = 0; r < 4; r++) {
            const int row = r0 + i * 16 + quad * 4 + r;
            const float inv = 1.0f / lrow[i][r];
            f16* orow = O + ((size_t)(b * Ssz) + row) * (NHs * HDs) + h * HDs;
#pragma unroll
            for (int jn = 0; jn < 16; jn++)
                orow[jn * 16 + l15] = (f16)(accO[i][jn][r] * inv);
        }
    }
}

// ---------------- launcher ----------------
extern "C" void kernel_launch(void* const* d_in, const int* in_sizes, int n_in,
                              void* d_out, int out_size, void* d_ws, size_t ws_size,
                              hipStream_t stream) {
    const float* hs   = (const float*)d_in[0];
    const float* Wq   = (const float*)d_in[1];
    const float* Wk   = (const float*)d_in[2];
    const float* Wv   = (const float*)d_in[3];
    const float* Wo   = (const float*)d_in[4];
    const float* cosb = (const float*)d_in[5];
    const float* sinb = (const float*)d_in[6];
    float* out = (float*)d_out;

    char* ws = (char*)d_ws;
    f16*   hs_h = (f16*)(ws);                    // 25165824 B
    f16*   w_h  = (f16*)(ws + 25165824);         // 25165824 B (reused per weight)
    float* proj = (float*)(ws + 50331648);       // 67108864 B (reused: qproj/kproj/vproj/attn_out)
    f16*   q_h  = (f16*)(ws + 117440512);        // 33554432 B
    f16*   k_h  = (f16*)(ws + 150994944);        // 16777216 B
    f16*   v_h  = (f16*)(ws + 167772160);        // 16777216 B  (total 184549376 B)
    f16*   ao_h = (f16*)proj;                    // attn output reuses proj region

    int n4;
    // 1) cast hidden states
    n4 = (Bsz * Ssz * HIDs) / 4;
    cast_f32_f16_v4<<<n4 / 256, 256, 0, stream>>>((const float4*)hs, (f16x4*)hs_h, n4);
    // 2) Q projection
    n4 = (NHs * HDs * HIDs) / 4;
    cast_f32_f16_v4<<<n4 / 256, 256, 0, stream>>>((const float4*)Wq, (f16x4*)w_h, n4);
    gemm_nt_f16<<<dim3(4096 / 128, 4096 / 128), 256, 0, stream>>>(hs_h, w_h, proj, 4096, 4096, 3072);
    rope_q_kernel<<<dim3(Ssz, NHs, Bsz), 256, 0, stream>>>(proj, cosb, sinb, q_h);
    // 3) K projection + quantize
    n4 = (NKVs * HDs * HIDs) / 4;
    cast_f32_f16_v4<<<n4 / 256, 256, 0, stream>>>((const float4*)Wk, (f16x4*)w_h, n4);
    gemm_nt_f16<<<dim3(2048 / 128, 4096 / 128), 256, 0, stream>>>(hs_h, w_h, proj, 4096, 2048, 3072);
    rope_quant_k_kernel<<<dim3(Ssz, NKVs, Bsz), 256, 0, stream>>>(proj, cosb, sinb, k_h);
    // 4) V projection + permute
    n4 = (NKVs * HDs * HIDs) / 4;
    cast_f32_f16_v4<<<n4 / 256, 256, 0, stream>>>((const float4*)Wv, (f16x4*)w_h, n4);
    gemm_nt_f16<<<dim3(2048 / 128, 4096 / 128), 256, 0, stream>>>(hs_h, w_h, proj, 4096, 2048, 3072);
    n4 = (Bsz * NKVs * Ssz * HDs) / 4;
    permute_v_kernel<<<n4 / 256, 256, 0, stream>>>((const float4*)proj, (f16x4*)v_h, n4);
    // 5) attention (writes ao_h = proj region, vproj already consumed)
    attn_kernel<<<dim3(Ssz / 32, NHs, Bsz), 64, 0, stream>>>(q_h, k_h, v_h, ao_h);
    // 6) output projection -> d_out
    n4 = (HIDs * NHs * HDs) / 4;
    cast_f32_f16_v4<<<n4 / 256, 256, 0, stream>>>((const float4*)Wo, (f16x4*)w_h, n4);
    gemm_nt_f16<<<dim3(3072 / 128, 4096 / 128), 256, 0, stream>>>(ao_h, w_h, out, 4096, 3072, 4096);
}

// Round 2
// 1200.298 us; speedup vs baseline: 1.2302x; 1.2302x over previous
//
#include <hip/hip_runtime.h>
#include <math.h>

#define Bsz 2
#define Ssz 2048
#define HIDs 3072
#define NHs 16
#define NKVs 8
#define HDs 256

typedef _Float16 f16;
typedef _Float16 f16x8 __attribute__((ext_vector_type(8)));
typedef _Float16 f16x4 __attribute__((ext_vector_type(4)));
typedef float f32x4 __attribute__((ext_vector_type(4)));

__device__ __forceinline__ void async16(const f16* g, f16* l) {
    __builtin_amdgcn_global_load_lds(
        (const __attribute__((address_space(1))) void*)g,
        (__attribute__((address_space(3))) void*)l, 16, 0, 0);
}

// ---------------- cast fp32 -> fp16 (vectorized x4) ----------------
__global__ void cast_f32_f16_v4(const float4* __restrict__ in, f16x4* __restrict__ out, int n4) {
    int i = blockIdx.x * blockDim.x + threadIdx.x;
    if (i < n4) {
        float4 v = in[i];
        f16x4 r;
        r[0] = (f16)v.x; r[1] = (f16)v.y; r[2] = (f16)v.z; r[3] = (f16)v.w;
        out[i] = r;
    }
}

// ---- NT GEMM (m97 structure): C[M,N] = A[M,K]*B[N,K]^T, f16 in, f32 out ----
// LDS unpadded stride 32 f16 (64B): b128 frag reads hit the 8-cyc bank floor.
__global__ __launch_bounds__(256) void gemm_nt_f16(
    const f16* __restrict__ A, const f16* __restrict__ Bm, float* __restrict__ C,
    int M, int N, int K)
{
    __shared__ __align__(16) f16 As[128 * 32];
    __shared__ __align__(16) f16 Bs[128 * 32];
    const int tid  = threadIdx.x;
    const int wave = tid >> 6, lane = tid & 63;
    const int l15  = lane & 15, quad = lane >> 4;
    const int m0 = blockIdx.y * 128, n0 = blockIdx.x * 128;
    const int wm = (wave >> 1) * 64, wn = (wave & 1) * 64;
    const int srow = wave * 32 + (lane >> 2);      // staging row within tile
    const int scol = (lane & 3) * 8;               // staging col (f16)

    f32x4 acc[4][4];
    const f32x4 fz = {0.f, 0.f, 0.f, 0.f};
#pragma unroll
    for (int i = 0; i < 4; i++)
#pragma unroll
        for (int j = 0; j < 4; j++) acc[i][j] = fz;

    const f16* Ag0 = A  + (size_t)(m0 + srow) * K + scol;
    const f16* Ag1 = A  + (size_t)(m0 + srow + 16) * K + scol;
    const f16* Bg0 = Bm + (size_t)(n0 + srow) * K + scol;
    const f16* Bg1 = Bm + (size_t)(n0 + srow + 16) * K + scol;
    f16* Al0 = As + (wave * 32) * 32;
    f16* Al1 = As + (wave * 32 + 16) * 32;
    f16* Bl0 = Bs + (wave * 32) * 32;
    f16* Bl1 = Bs + (wave * 32 + 16) * 32;

    for (int k0 = 0; k0 < K; k0 += 32) {
        __syncthreads();
        async16(Ag0 + k0, Al0);
        async16(Ag1 + k0, Al1);
        async16(Bg0 + k0, Bl0);
        async16(Bg1 + k0, Bl1);
        __syncthreads();
        f16x8 af[4], bfr[4];
#pragma unroll
        for (int i = 0; i < 4; i++)
            af[i] = *(const f16x8*)(As + (wm + i * 16 + l15) * 32 + quad * 8);
#pragma unroll
        for (int j = 0; j < 4; j++)
            bfr[j] = *(const f16x8*)(Bs + (wn + j * 16 + l15) * 32 + quad * 8);
#pragma unroll
        for (int i = 0; i < 4; i++)
#pragma unroll
            for (int j = 0; j < 4; j++)
                acc[i][j] = __builtin_amdgcn_mfma_f32_16x16x32_f16(af[i], bfr[j], acc[i][j], 0, 0, 0);
    }
#pragma unroll
    for (int i = 0; i < 4; i++) {
        const int r = m0 + wm + i * 16 + quad * 4;
#pragma unroll
        for (int j = 0; j < 4; j++) {
            const int c = n0 + wn + j * 16 + l15;
#pragma unroll
            for (int rr = 0; rr < 4; rr++)
                C[(size_t)(r + rr) * N + c] = acc[i][j][rr];
        }
    }
}

// ---------------- RoPE for Q (scale 1/sqrt(HD) folded in) ----------------
__global__ void rope_q_kernel(const float* __restrict__ qp, const float* __restrict__ cosb,
                              const float* __restrict__ sinb, f16* __restrict__ qo) {
    const int s = blockIdx.x, h = blockIdx.y, b = blockIdx.z;
    const int d = threadIdx.x;
    const float* row = qp + (size_t)(b * Ssz + s) * (NHs * HDs) + h * HDs;
    float x = row[d];
    float other = (d < 128) ? -row[d + 128] : row[d - 128];
    float val = (x * cosb[s * HDs + d] + other * sinb[s * HDs + d]) * 0.0625f;
    qo[((size_t)(b * NHs + h) * Ssz + s) * HDs + d] = (f16)val;
}

// ---------------- RoPE + BFP4 quantize for K ----------------
__global__ void rope_quant_k_kernel(const float* __restrict__ kp, const float* __restrict__ cosb,
                                    const float* __restrict__ sinb, f16* __restrict__ ko) {
    const int s = blockIdx.x, h = blockIdx.y, b = blockIdx.z;
    const int d = threadIdx.x;
    const float* row = kp + (size_t)(b * Ssz + s) * (NKVs * HDs) + h * HDs;
    float x = row[d];
    float other = (d < 128) ? -row[d + 128] : row[d - 128];
    float val = x * cosb[s * HDs + d] + other * sinb[s * HDs + d];
    __shared__ float red[256];
    red[d] = fabsf(val);
    __syncthreads();
    for (int off = 64; off >= 1; off >>= 1) {
        if ((d & 127) < off) red[d] = fmaxf(red[d], red[d + off]);
        __syncthreads();
    }
    float maxabs = red[d & 128];
    float out;
    if (maxabs > 0.f) {
        int ex;
        frexpf(maxabs, &ex);                 // floor(log2(maxabs)) = ex-1 exactly
        float scale = ldexpf(1.0f, ex - 3);  // 2^(e - (bits-2)), bits=4
        float q = rintf(val / scale);
        q = fminf(7.f, fmaxf(-7.f, q));
        out = q * scale;
    } else out = 0.f;
    ko[((size_t)(b * NKVs + h) * Ssz + s) * HDs + d] = (f16)out;
}

// -------- V: fp32 proj [b][s][kh*256+d] -> f16 Vt [b][kh][d][s] (transposed) --------
__global__ __launch_bounds__(256) void transpose_v_kernel(
    const float* __restrict__ proj, f16* __restrict__ vt)
{
    const int s0 = blockIdx.x * 64, c0 = blockIdx.y * 64, b = blockIdx.z;
    const int tid = threadIdx.x;
    __shared__ f16 T[64 * 72];
    {
        const int r = tid >> 2, cc = (tid & 3) * 16;
        const float* src = proj + (size_t)(b * Ssz + s0 + r) * (NKVs * HDs) + c0 + cc;
        f16 tmp[16];
#pragma unroll
        for (int q4 = 0; q4 < 4; q4++) {
            float4 v = *(const float4*)(src + q4 * 4);
            tmp[q4 * 4 + 0] = (f16)v.x; tmp[q4 * 4 + 1] = (f16)v.y;
            tmp[q4 * 4 + 2] = (f16)v.z; tmp[q4 * 4 + 3] = (f16)v.w;
        }
        *(f16x8*)(T + r * 72 + cc)     = *(f16x8*)(tmp);
        *(f16x8*)(T + r * 72 + cc + 8) = *(f16x8*)(tmp + 8);
    }
    __syncthreads();
    {
        const int d = tid >> 2, sc = (tid & 3) * 16;
        f16 tmp[16];
#pragma unroll
        for (int j = 0; j < 16; j++) tmp[j] = T[(sc + j) * 72 + d];
        const int col = c0 + d;
        const int kh = col >> 8, dd = col & 255;
        f16* dst = vt + ((size_t)(b * NKVs + kh) * HDs + dd) * Ssz + s0 + sc;
        *(f16x8*)(dst)     = *(f16x8*)(tmp);
        *(f16x8*)(dst + 8) = *(f16x8*)(tmp + 8);
    }
}

// ---------------- flash attention v2: 256 thr, Q-tile 128, KT 32 ----------------
__global__ __launch_bounds__(256) void attn_kernel(
    const f16* __restrict__ Q,   // [B][NH][S][HD], pre-scaled by 1/16
    const f16* __restrict__ Kq,  // [B][NKV][S][HD] quantized
    const f16* __restrict__ Vt,  // [B][NKV][HD][S] transposed
    f16* __restrict__ O)         // [B][S][NH*HD]
{
    const int qt = (gridDim.x - 1) - blockIdx.x;   // longest blocks first
    const int h = blockIdx.y, b = blockIdx.z;
    const int kh = h >> 1;
    const int tid = threadIdx.x;
    const int wave = tid >> 6, lane = tid & 63;
    const int l15 = lane & 15, quad = lane >> 4;
    const int wrow = qt * 128 + wave * 32;         // wave's first Q row

    const f16* Qb  = Q  + ((size_t)(b * NHs  + h)  * Ssz) * HDs;
    const f16* Kg  = Kq + ((size_t)(b * NKVs + kh) * Ssz) * HDs;
    const f16* Vtg = Vt + ((size_t)(b * NKVs + kh) * HDs) * Ssz;

    __shared__ __align__(16) f16 Ks[32 * 256];   // [kv][d], chunks XOR-swizzled
    __shared__ __align__(16) f16 Vs[256 * 32];   // [d][kv], 64B stride = bank floor
    __shared__ __align__(16) f16 Pl[4 * 32 * 40];
    f16* Pw = Pl + wave * 32 * 40;

    // staging lane maps (constant per thread)
    const int k_r   = lane >> 5;                  // row within pair
    const int k_cs  = (lane & 31) ^ (k_r << 2);   // swizzled global chunk
    const int v_r   = lane >> 2;                  // d row within 16-group
    const int v_c   = (lane & 3) * 8;             // kv col (f16)

    f16x8 qf[2][8];
#pragma unroll
    for (int i = 0; i < 2; i++) {
        const f16* qrow = Qb + (size_t)(wrow + i * 16 + l15) * HDs + quad * 8;
#pragma unroll
        for (int ks = 0; ks < 8; ks++)
            qf[i][ks] = *(const f16x8*)(qrow + ks * 32);
    }

    const f32x4 fz = {0.f, 0.f, 0.f, 0.f};
    f32x4 accO[2][16];
#pragma unroll
    for (int i = 0; i < 2; i++)
#pragma unroll
        for (int jn = 0; jn < 16; jn++) accO[i][jn] = fz;
    float mrow[2][4], lrow[2][4];
#pragma unroll
    for (int i = 0; i < 2; i++)
#pragma unroll
        for (int r = 0; r < 4; r++) { mrow[i][r] = -1e30f; lrow[i][r] = 0.f; }

    const int nk = 4 * qt + 4;
    const int wave_max_row = wrow + 31;

    for (int kt = 0; kt < nk; kt++) {
        const int kvb = kt * 32;
        __syncthreads();   // previous tile fully consumed
        // stage K: 8 rows per wave, 2 rows per instr, XOR-swizzled chunks
#pragma unroll
        for (int t = 0; t < 4; t++) {
            const int r2 = wave * 8 + t * 2;
            async16(Kg + (size_t)(kvb + r2 + k_r) * 256 + k_cs * 8,
                    Ks + r2 * 256);
        }
        // stage Vt: 64 d-rows per wave, 16 rows per instr
#pragma unroll
        for (int t = 0; t < 4; t++) {
            const int d0 = wave * 64 + t * 16;
            async16(Vtg + (size_t)(d0 + v_r) * Ssz + kvb + v_c,
                    Vs + d0 * 32);
        }
        __syncthreads();   // drains vmcnt(0) before LDS reads

        if (kvb <= wave_max_row) {
            f32x4 sv[2][2];
#pragma unroll
            for (int i = 0; i < 2; i++) { sv[i][0] = fz; sv[i][1] = fz; }
            const int sw0 = (l15 & 1) << 2;   // read-side chunk swizzle
#pragma unroll
            for (int ks = 0; ks < 8; ks++) {
                const int cpos = ((ks * 4 + quad) ^ sw0) * 8;
                f16x8 kf0 = *(const f16x8*)(Ks + l15 * 256 + cpos);
                f16x8 kf1 = *(const f16x8*)(Ks + (16 + l15) * 256 + cpos);
#pragma unroll
                for (int i = 0; i < 2; i++) {
                    sv[i][0] = __builtin_amdgcn_mfma_f32_16x16x32_f16(qf[i][ks], kf0, sv[i][0], 0, 0, 0);
                    sv[i][1] = __builtin_amdgcn_mfma_f32_16x16x32_f16(qf[i][ks], kf1, sv[i][1], 0, 0, 0);
                }
            }
            float alpha[2][4];
#pragma unroll
            for (int i = 0; i < 2; i++) {
#pragma unroll
                for (int r = 0; r < 4; r++) {
                    float s0 = sv[i][0][r], s1 = sv[i][1][r];
                    const int row = wrow + i * 16 + quad * 4 + r;
                    if (kvb + 31 > row) {   // diagonal tile for this wave
                        if (kvb + l15 > row)      s0 = -1e30f;
                        if (kvb + 16 + l15 > row) s1 = -1e30f;
                    }
                    float rmax = fmaxf(s0, s1);
                    rmax = fmaxf(rmax, __shfl_xor(rmax, 8));
                    rmax = fmaxf(rmax, __shfl_xor(rmax, 4));
                    rmax = fmaxf(rmax, __shfl_xor(rmax, 2));
                    rmax = fmaxf(rmax, __shfl_xor(rmax, 1));
                    float mold = mrow[i][r];
                    float mnew = fmaxf(mold, rmax);
                    float a  = __expf(mold - mnew);
                    float p0 = __expf(s0 - mnew);
                    float p1 = __expf(s1 - mnew);
                    float rs = p0 + p1;
                    rs += __shfl_xor(rs, 8);
                    rs += __shfl_xor(rs, 4);
                    rs += __shfl_xor(rs, 2);
                    rs += __shfl_xor(rs, 1);
                    lrow[i][r] = lrow[i][r] * a + rs;
                    mrow[i][r] = mnew;
                    alpha[i][r] = a;
                    Pw[(i * 16 + quad * 4 + r) * 40 + l15]      = (f16)p0;
                    Pw[(i * 16 + quad * 4 + r) * 40 + 16 + l15] = (f16)p1;
                }
            }
#pragma unroll
            for (int i = 0; i < 2; i++)
#pragma unroll
                for (int jn = 0; jn < 16; jn++) {
                    f32x4 t = accO[i][jn];
                    t[0] *= alpha[i][0]; t[1] *= alpha[i][1];
                    t[2] *= alpha[i][2]; t[3] *= alpha[i][3];
                    accO[i][jn] = t;
                }
            // P (C-layout) -> A-layout via same-wave LDS round trip
            f16x8 pf0 = *(const f16x8*)(Pw + l15 * 40 + quad * 8);
            f16x8 pf1 = *(const f16x8*)(Pw + (16 + l15) * 40 + quad * 8);
#pragma unroll
            for (int jn = 0; jn < 16; jn++) {
                f16x8 vf = *(const f16x8*)(Vs + (jn * 16 + l15) * 32 + quad * 8);
                accO[0][jn] = __builtin_amdgcn_mfma_f32_16x16x32_f16(pf0, vf, accO[0][jn], 0, 0, 0);
                accO[1][jn] = __builtin_amdgcn_mfma_f32_16x16x32_f16(pf1, vf, accO[1][jn], 0, 0, 0);
            }
        }
    }
#pragma unroll
    for (int i = 0; i < 2; i++) {
#pragma unroll
        for (int r = 0; r < 4; r++) {
            const int row = wrow + i * 16 + quad * 4 + r;
            const float inv = 1.0f / lrow[i][r];
            f16* orow = O + ((size_t)(b * Ssz) + row) * (NHs * HDs) + h * HDs;
#pragma unroll
            for (int jn = 0; jn < 16; jn++)
                orow[jn * 16 + l15] = (f16)(accO[i][jn][r] * inv);
        }
    }
}

// ---------------- launcher ----------------
extern "C" void kernel_launch(void* const* d_in, const int* in_sizes, int n_in,
                              void* d_out, int out_size, void* d_ws, size_t ws_size,
                              hipStream_t stream) {
    const float* hs   = (const float*)d_in[0];
    const float* Wq   = (const float*)d_in[1];
    const float* Wk   = (const float*)d_in[2];
    const float* Wv   = (const float*)d_in[3];
    const float* Wo   = (const float*)d_in[4];
    const float* cosb = (const float*)d_in[5];
    const float* sinb = (const float*)d_in[6];
    float* out = (float*)d_out;

    char* ws = (char*)d_ws;
    f16*   hs_h = (f16*)(ws);                    // 25165824 B
    f16*   w_h  = (f16*)(ws + 25165824);         // 25165824 B (reused per weight)
    float* proj = (float*)(ws + 50331648);       // 67108864 B (reused)
    f16*   q_h  = (f16*)(ws + 117440512);        // 33554432 B
    f16*   k_h  = (f16*)(ws + 150994944);        // 16777216 B
    f16*   vt_h = (f16*)(ws + 167772160);        // 16777216 B
    f16*   ao_h = (f16*)proj;                    // attn output reuses proj region

    int n4;
    n4 = (Bsz * Ssz * HIDs) / 4;
    cast_f32_f16_v4<<<n4 / 256, 256, 0, stream>>>((const float4*)hs, (f16x4*)hs_h, n4);
    // Q projection
    n4 = (NHs * HDs * HIDs) / 4;
    cast_f32_f16_v4<<<n4 / 256, 256, 0, stream>>>((const float4*)Wq, (f16x4*)w_h, n4);
    gemm_nt_f16<<<dim3(4096 / 128, 4096 / 128), 256, 0, stream>>>(hs_h, w_h, proj, 4096, 4096, 3072);
    rope_q_kernel<<<dim3(Ssz, NHs, Bsz), 256, 0, stream>>>(proj, cosb, sinb, q_h);
    // K projection + quantize
    n4 = (NKVs * HDs * HIDs) / 4;
    cast_f32_f16_v4<<<n4 / 256, 256, 0, stream>>>((const float4*)Wk, (f16x4*)w_h, n4);
    gemm_nt_f16<<<dim3(2048 / 128, 4096 / 128), 256, 0, stream>>>(hs_h, w_h, proj, 4096, 2048, 3072);
    rope_quant_k_kernel<<<dim3(Ssz, NKVs, Bsz), 256, 0, stream>>>(proj, cosb, sinb, k_h);
    // V projection + transpose
    n4 = (NKVs * HDs * HIDs) / 4;
    cast_f32_f16_v4<<<n4 / 256, 256, 0, stream>>>((const float4*)Wv, (f16x4*)w_h, n4);
    gemm_nt_f16<<<dim3(2048 / 128, 4096 / 128), 256, 0, stream>>>(hs_h, w_h, proj, 4096, 2048, 3072);
    transpose_v_kernel<<<dim3(Ssz / 64, (NKVs * HDs) / 64, Bsz), 256, 0, stream>>>(proj, vt_h);
    // attention
    attn_kernel<<<dim3(Ssz / 128, NHs, Bsz), 256, 0, stream>>>(q_h, k_h, vt_h, ao_h);
    // output projection -> d_out
    n4 = (HIDs * NHs * HDs) / 4;
    cast_f32_f16_v4<<<n4 / 256, 256, 0, stream>>>((const float4*)Wo, (f16x4*)w_h, n4);
    gemm_nt_f16<<<dim3(3072 / 128, 4096 / 128), 256, 0, stream>>>(ao_h, w_h, out, 4096, 3072, 4096);
}

// Round 3
// 1020.755 us; speedup vs baseline: 1.4466x; 1.1759x over previous
//
#include <hip/hip_runtime.h>
#include <math.h>

#define Bsz 2
#define Ssz 2048
#define HIDs 3072
#define NHs 16
#define NKVs 8
#define HDs 256

typedef _Float16 f16;
typedef _Float16 f16x8 __attribute__((ext_vector_type(8)));
typedef _Float16 f16x4 __attribute__((ext_vector_type(4)));
typedef float f32x4 __attribute__((ext_vector_type(4)));

__device__ __forceinline__ void async16(const f16* g, f16* l) {
    __builtin_amdgcn_global_load_lds(
        (const __attribute__((address_space(1))) void*)g,
        (__attribute__((address_space(3))) void*)l, 16, 0, 0);
}

// 16-lane (row) reductions on the VALU pipe via DPP row_ror — keeps softmax
// cross-lane traffic OFF the LDS pipe that feeds MFMA fragments.
__device__ __forceinline__ float row_max16(float v) {
    int t;
    t = __builtin_amdgcn_mov_dpp(__float_as_int(v), 0x121, 0xf, 0xf, false);
    v = fmaxf(v, __int_as_float(t));
    t = __builtin_amdgcn_mov_dpp(__float_as_int(v), 0x122, 0xf, 0xf, false);
    v = fmaxf(v, __int_as_float(t));
    t = __builtin_amdgcn_mov_dpp(__float_as_int(v), 0x124, 0xf, 0xf, false);
    v = fmaxf(v, __int_as_float(t));
    t = __builtin_amdgcn_mov_dpp(__float_as_int(v), 0x128, 0xf, 0xf, false);
    v = fmaxf(v, __int_as_float(t));
    return v;
}
__device__ __forceinline__ float row_sum16(float v) {
    int t;
    t = __builtin_amdgcn_mov_dpp(__float_as_int(v), 0x121, 0xf, 0xf, false);
    v = v + __int_as_float(t);
    t = __builtin_amdgcn_mov_dpp(__float_as_int(v), 0x122, 0xf, 0xf, false);
    v = v + __int_as_float(t);
    t = __builtin_amdgcn_mov_dpp(__float_as_int(v), 0x124, 0xf, 0xf, false);
    v = v + __int_as_float(t);
    t = __builtin_amdgcn_mov_dpp(__float_as_int(v), 0x128, 0xf, 0xf, false);
    v = v + __int_as_float(t);
    return v;
}

// ---------------- cast fp32 -> fp16 (vectorized x4) ----------------
__global__ void cast_f32_f16_v4(const float4* __restrict__ in, f16x4* __restrict__ out, int n4) {
    int i = blockIdx.x * blockDim.x + threadIdx.x;
    if (i < n4) {
        float4 v = in[i];
        f16x4 r;
        r[0] = (f16)v.x; r[1] = (f16)v.y; r[2] = (f16)v.z; r[3] = (f16)v.w;
        out[i] = r;
    }
}

// ---- NT GEMM (m97 structure): C[M,N] = A[M,K]*B[N,K]^T, f16 in, f32 out ----
__global__ __launch_bounds__(256) void gemm_nt_f16(
    const f16* __restrict__ A, const f16* __restrict__ Bm, float* __restrict__ C,
    int M, int N, int K)
{
    __shared__ __align__(16) f16 As[128 * 32];
    __shared__ __align__(16) f16 Bs[128 * 32];
    const int tid  = threadIdx.x;
    const int wave = tid >> 6, lane = tid & 63;
    const int l15  = lane & 15, quad = lane >> 4;
    const int m0 = blockIdx.y * 128, n0 = blockIdx.x * 128;
    const int wm = (wave >> 1) * 64, wn = (wave & 1) * 64;
    const int srow = wave * 32 + (lane >> 2);
    const int scol = (lane & 3) * 8;

    f32x4 acc[4][4];
    const f32x4 fz = {0.f, 0.f, 0.f, 0.f};
#pragma unroll
    for (int i = 0; i < 4; i++)
#pragma unroll
        for (int j = 0; j < 4; j++) acc[i][j] = fz;

    const f16* Ag0 = A  + (size_t)(m0 + srow) * K + scol;
    const f16* Ag1 = A  + (size_t)(m0 + srow + 16) * K + scol;
    const f16* Bg0 = Bm + (size_t)(n0 + srow) * K + scol;
    const f16* Bg1 = Bm + (size_t)(n0 + srow + 16) * K + scol;
    f16* Al0 = As + (wave * 32) * 32;
    f16* Al1 = As + (wave * 32 + 16) * 32;
    f16* Bl0 = Bs + (wave * 32) * 32;
    f16* Bl1 = Bs + (wave * 32 + 16) * 32;

    for (int k0 = 0; k0 < K; k0 += 32) {
        __syncthreads();
        async16(Ag0 + k0, Al0);
        async16(Ag1 + k0, Al1);
        async16(Bg0 + k0, Bl0);
        async16(Bg1 + k0, Bl1);
        __syncthreads();
        f16x8 af[4], bfr[4];
#pragma unroll
        for (int i = 0; i < 4; i++)
            af[i] = *(const f16x8*)(As + (wm + i * 16 + l15) * 32 + quad * 8);
#pragma unroll
        for (int j = 0; j < 4; j++)
            bfr[j] = *(const f16x8*)(Bs + (wn + j * 16 + l15) * 32 + quad * 8);
#pragma unroll
        for (int i = 0; i < 4; i++)
#pragma unroll
            for (int j = 0; j < 4; j++)
                acc[i][j] = __builtin_amdgcn_mfma_f32_16x16x32_f16(af[i], bfr[j], acc[i][j], 0, 0, 0);
    }
#pragma unroll
    for (int i = 0; i < 4; i++) {
        const int r = m0 + wm + i * 16 + quad * 4;
#pragma unroll
        for (int j = 0; j < 4; j++) {
            const int c = n0 + wn + j * 16 + l15;
#pragma unroll
            for (int rr = 0; rr < 4; rr++)
                C[(size_t)(r + rr) * N + c] = acc[i][j][rr];
        }
    }
}

// ---------------- RoPE for Q (scale 1/sqrt(HD) folded in) ----------------
__global__ void rope_q_kernel(const float* __restrict__ qp, const float* __restrict__ cosb,
                              const float* __restrict__ sinb, f16* __restrict__ qo) {
    const int s = blockIdx.x, h = blockIdx.y, b = blockIdx.z;
    const int d = threadIdx.x;
    const float* row = qp + (size_t)(b * Ssz + s) * (NHs * HDs) + h * HDs;
    float x = row[d];
    float other = (d < 128) ? -row[d + 128] : row[d - 128];
    float val = (x * cosb[s * HDs + d] + other * sinb[s * HDs + d]) * 0.0625f;
    qo[((size_t)(b * NHs + h) * Ssz + s) * HDs + d] = (f16)val;
}

// ---------------- RoPE + BFP4 quantize for K ----------------
__global__ void rope_quant_k_kernel(const float* __restrict__ kp, const float* __restrict__ cosb,
                                    const float* __restrict__ sinb, f16* __restrict__ ko) {
    const int s = blockIdx.x, h = blockIdx.y, b = blockIdx.z;
    const int d = threadIdx.x;
    const float* row = kp + (size_t)(b * Ssz + s) * (NKVs * HDs) + h * HDs;
    float x = row[d];
    float other = (d < 128) ? -row[d + 128] : row[d - 128];
    float val = x * cosb[s * HDs + d] + other * sinb[s * HDs + d];
    __shared__ float red[256];
    red[d] = fabsf(val);
    __syncthreads();
    for (int off = 64; off >= 1; off >>= 1) {
        if ((d & 127) < off) red[d] = fmaxf(red[d], red[d + off]);
        __syncthreads();
    }
    float maxabs = red[d & 128];
    float out;
    if (maxabs > 0.f) {
        int ex;
        frexpf(maxabs, &ex);                 // floor(log2(maxabs)) = ex-1 exactly
        float scale = ldexpf(1.0f, ex - 3);  // 2^(e - (bits-2)), bits=4
        float q = rintf(val / scale);
        q = fminf(7.f, fmaxf(-7.f, q));
        out = q * scale;
    } else out = 0.f;
    ko[((size_t)(b * NKVs + h) * Ssz + s) * HDs + d] = (f16)out;
}

// -------- V: fp32 proj [b][s][kh*256+d] -> f16 Vt [b][kh][d][s] (transposed) --------
__global__ __launch_bounds__(256) void transpose_v_kernel(
    const float* __restrict__ proj, f16* __restrict__ vt)
{
    const int s0 = blockIdx.x * 64, c0 = blockIdx.y * 64, b = blockIdx.z;
    const int tid = threadIdx.x;
    __shared__ f16 T[64 * 72];
    {
        const int r = tid >> 2, cc = (tid & 3) * 16;
        const float* src = proj + (size_t)(b * Ssz + s0 + r) * (NKVs * HDs) + c0 + cc;
        f16 tmp[16];
#pragma unroll
        for (int q4 = 0; q4 < 4; q4++) {
            float4 v = *(const float4*)(src + q4 * 4);
            tmp[q4 * 4 + 0] = (f16)v.x; tmp[q4 * 4 + 1] = (f16)v.y;
            tmp[q4 * 4 + 2] = (f16)v.z; tmp[q4 * 4 + 3] = (f16)v.w;
        }
        *(f16x8*)(T + r * 72 + cc)     = *(f16x8*)(tmp);
        *(f16x8*)(T + r * 72 + cc + 8) = *(f16x8*)(tmp + 8);
    }
    __syncthreads();
    {
        const int d = tid >> 2, sc = (tid & 3) * 16;
        f16 tmp[16];
#pragma unroll
        for (int j = 0; j < 16; j++) tmp[j] = T[(sc + j) * 72 + d];
        const int col = c0 + d;
        const int kh = col >> 8, dd = col & 255;
        f16* dst = vt + ((size_t)(b * NKVs + kh) * HDs + dd) * Ssz + s0 + sc;
        *(f16x8*)(dst)     = *(f16x8*)(tmp);
        *(f16x8*)(dst + 8) = *(f16x8*)(tmp + 8);
    }
}

// -------- flash attention v3: 256 thr, 16 Q-rows/wave, Q-tile 64, KV-tile 32 --------
// Registers: accO 64 + qf 32 + temps ~80 -> 2 waves/SIMD -> 2 blocks/CU (8 waves).
__global__ __launch_bounds__(256, 2) void attn_kernel(
    const f16* __restrict__ Q,   // [B][NH][S][HD], pre-scaled by 1/16
    const f16* __restrict__ Kq,  // [B][NKV][S][HD] quantized
    const f16* __restrict__ Vt,  // [B][NKV][HD][S] transposed
    f16* __restrict__ O)         // [B][S][NH*HD]
{
    const int qt = (gridDim.x - 1) - blockIdx.x;   // longest blocks first
    const int h = blockIdx.y, b = blockIdx.z;
    const int kh = h >> 1;
    const int tid = threadIdx.x;
    const int wave = tid >> 6, lane = tid & 63;
    const int l15 = lane & 15, quad = lane >> 4;
    const int wrow = qt * 64 + wave * 16;          // wave's first Q row

    const f16* Qb  = Q  + ((size_t)(b * NHs  + h)  * Ssz) * HDs;
    const f16* Kg  = Kq + ((size_t)(b * NKVs + kh) * Ssz) * HDs;
    const f16* Vtg = Vt + ((size_t)(b * NKVs + kh) * HDs) * Ssz;

    __shared__ __align__(16) f16 Ks[32 * 256];   // [kv][d], chunks XOR-swizzled
    __shared__ __align__(16) f16 Vs[256 * 32];   // [d][kv]
    __shared__ __align__(16) f16 Pl[4 * 16 * 40];
    f16* Pw = Pl + wave * 16 * 40;

    const int k_r   = lane >> 5;
    const int k_cs  = (lane & 31) ^ (k_r << 2);
    const int v_r   = lane >> 2;
    const int v_c   = (lane & 3) * 8;

    f16x8 qf[8];
    {
        const f16* qrow = Qb + (size_t)(wrow + l15) * HDs + quad * 8;
#pragma unroll
        for (int ks = 0; ks < 8; ks++)
            qf[ks] = *(const f16x8*)(qrow + ks * 32);
    }

    const f32x4 fz = {0.f, 0.f, 0.f, 0.f};
    f32x4 accO[16];
#pragma unroll
    for (int jn = 0; jn < 16; jn++) accO[jn] = fz;
    float mrow[4], lpart[4];
#pragma unroll
    for (int r = 0; r < 4; r++) { mrow[r] = -1e30f; lpart[r] = 0.f; }

    const int nk = 2 * qt + 2;
    const int wave_max_row = wrow + 15;

    for (int kt = 0; kt < nk; kt++) {
        const int kvb = kt * 32;
        __syncthreads();
#pragma unroll
        for (int t = 0; t < 4; t++) {
            const int r2 = wave * 8 + t * 2;
            async16(Kg + (size_t)(kvb + r2 + k_r) * 256 + k_cs * 8, Ks + r2 * 256);
        }
#pragma unroll
        for (int t = 0; t < 4; t++) {
            const int d0 = wave * 64 + t * 16;
            async16(Vtg + (size_t)(d0 + v_r) * Ssz + kvb + v_c, Vs + d0 * 32);
        }
        __syncthreads();

        if (kvb <= wave_max_row) {
            f32x4 sv0 = fz, sv1 = fz;
            const int sw0 = (l15 & 1) << 2;
#pragma unroll
            for (int ks = 0; ks < 8; ks++) {
                const int cpos = ((ks * 4 + quad) ^ sw0) * 8;
                f16x8 kf0 = *(const f16x8*)(Ks + l15 * 256 + cpos);
                f16x8 kf1 = *(const f16x8*)(Ks + (16 + l15) * 256 + cpos);
                sv0 = __builtin_amdgcn_mfma_f32_16x16x32_f16(qf[ks], kf0, sv0, 0, 0, 0);
                sv1 = __builtin_amdgcn_mfma_f32_16x16x32_f16(qf[ks], kf1, sv1, 0, 0, 0);
            }
            float aup[4];
            bool need = false;
#pragma unroll
            for (int r = 0; r < 4; r++) {
                float s0 = sv0[r], s1 = sv1[r];
                const int row = wrow + quad * 4 + r;
                if (kvb + 31 > row) {
                    if (kvb + l15 > row)      s0 = -1e30f;
                    if (kvb + 16 + l15 > row) s1 = -1e30f;
                }
                float rmax = row_max16(fmaxf(s0, s1));
                float mold = mrow[r];
                float mnew = fmaxf(mold, rmax);
                aup[r] = __expf(mold - mnew);
                need = need || (mnew > mold);
                float p0 = __expf(s0 - mnew);
                float p1 = __expf(s1 - mnew);
                lpart[r] = lpart[r] * aup[r] + (p0 + p1);   // lane-local partial sum
                mrow[r] = mnew;
                Pw[(quad * 4 + r) * 40 + l15]      = (f16)p0;
                Pw[(quad * 4 + r) * 40 + 16 + l15] = (f16)p1;
            }
            if (__any(need)) {                               // rare after warm-up
#pragma unroll
                for (int jn = 0; jn < 16; jn++) {
                    f32x4 t = accO[jn];
                    t[0] *= aup[0]; t[1] *= aup[1]; t[2] *= aup[2]; t[3] *= aup[3];
                    accO[jn] = t;
                }
            }
            // P (C-layout) -> A-layout via same-wave LDS round trip
            f16x8 pf = *(const f16x8*)(Pw + l15 * 40 + quad * 8);
#pragma unroll
            for (int jn = 0; jn < 16; jn++) {
                f16x8 vf = *(const f16x8*)(Vs + (jn * 16 + l15) * 32 + quad * 8);
                accO[jn] = __builtin_amdgcn_mfma_f32_16x16x32_f16(pf, vf, accO[jn], 0, 0, 0);
            }
        }
    }
#pragma unroll
    for (int r = 0; r < 4; r++) {
        const int row = wrow + quad * 4 + r;
        const float inv = 1.0f / row_sum16(lpart[r]);
        f16* orow = O + ((size_t)(b * Ssz) + row) * (NHs * HDs) + h * HDs;
#pragma unroll
        for (int jn = 0; jn < 16; jn++)
            orow[jn * 16 + l15] = (f16)(accO[jn][r] * inv);
    }
}

// ---------------- launcher ----------------
extern "C" void kernel_launch(void* const* d_in, const int* in_sizes, int n_in,
                              void* d_out, int out_size, void* d_ws, size_t ws_size,
                              hipStream_t stream) {
    const float* hs   = (const float*)d_in[0];
    const float* Wq   = (const float*)d_in[1];
    const float* Wk   = (const float*)d_in[2];
    const float* Wv   = (const float*)d_in[3];
    const float* Wo   = (const float*)d_in[4];
    const float* cosb = (const float*)d_in[5];
    const float* sinb = (const float*)d_in[6];
    float* out = (float*)d_out;

    char* ws = (char*)d_ws;
    f16*   hs_h = (f16*)(ws);                    // 25165824 B
    f16*   w_h  = (f16*)(ws + 25165824);         // 25165824 B (reused per weight)
    float* proj = (float*)(ws + 50331648);       // 67108864 B (reused)
    f16*   q_h  = (f16*)(ws + 117440512);        // 33554432 B
    f16*   k_h  = (f16*)(ws + 150994944);        // 16777216 B
    f16*   vt_h = (f16*)(ws + 167772160);        // 16777216 B
    f16*   ao_h = (f16*)proj;                    // attn output reuses proj region

    int n4;
    n4 = (Bsz * Ssz * HIDs) / 4;
    cast_f32_f16_v4<<<n4 / 256, 256, 0, stream>>>((const float4*)hs, (f16x4*)hs_h, n4);
    // Q projection
    n4 = (NHs * HDs * HIDs) / 4;
    cast_f32_f16_v4<<<n4 / 256, 256, 0, stream>>>((const float4*)Wq, (f16x4*)w_h, n4);
    gemm_nt_f16<<<dim3(4096 / 128, 4096 / 128), 256, 0, stream>>>(hs_h, w_h, proj, 4096, 4096, 3072);
    rope_q_kernel<<<dim3(Ssz, NHs, Bsz), 256, 0, stream>>>(proj, cosb, sinb, q_h);
    // K projection + quantize
    n4 = (NKVs * HDs * HIDs) / 4;
    cast_f32_f16_v4<<<n4 / 256, 256, 0, stream>>>((const float4*)Wk, (f16x4*)w_h, n4);
    gemm_nt_f16<<<dim3(2048 / 128, 4096 / 128), 256, 0, stream>>>(hs_h, w_h, proj, 4096, 2048, 3072);
    rope_quant_k_kernel<<<dim3(Ssz, NKVs, Bsz), 256, 0, stream>>>(proj, cosb, sinb, k_h);
    // V projection + transpose
    n4 = (NKVs * HDs * HIDs) / 4;
    cast_f32_f16_v4<<<n4 / 256, 256, 0, stream>>>((const float4*)Wv, (f16x4*)w_h, n4);
    gemm_nt_f16<<<dim3(2048 / 128, 4096 / 128), 256, 0, stream>>>(hs_h, w_h, proj, 4096, 2048, 3072);
    transpose_v_kernel<<<dim3(Ssz / 64, (NKVs * HDs) / 64, Bsz), 256, 0, stream>>>(proj, vt_h);
    // attention: Q-tile 64 -> 1024 blocks, longest-first
    attn_kernel<<<dim3(Ssz / 64, NHs, Bsz), 256, 0, stream>>>(q_h, k_h, vt_h, ao_h);
    // output projection -> d_out
    n4 = (HIDs * NHs * HDs) / 4;
    cast_f32_f16_v4<<<n4 / 256, 256, 0, stream>>>((const float4*)Wo, (f16x4*)w_h, n4);
    gemm_nt_f16<<<dim3(3072 / 128, 4096 / 128), 256, 0, stream>>>(ao_h, w_h, out, 4096, 3072, 4096);
}